// Round 1
// baseline (4779.751 us; speedup 1.0000x reference)
//
#include <hip/hip_runtime.h>
#include <stdint.h>
#include <stddef.h>

#define T_STEPS 1024
#define BATCH   512
#define HID     256
#define DIN     64

typedef __attribute__((ext_vector_type(8))) short short8;
typedef __attribute__((ext_vector_type(4))) short short4v;
typedef __attribute__((ext_vector_type(2))) short short2v;
typedef __attribute__((ext_vector_type(4))) float float4v;

static __device__ __forceinline__ short f2bf(float f) {
  union { float f; unsigned u; } v; v.f = f;
  unsigned r = (v.u + 0x7FFFu + ((v.u >> 16) & 1u)) >> 16;
  return (short)r;
}
static __device__ __forceinline__ float sigm(float x) {
  return 1.0f / (1.0f + __expf(-x));
}
static __device__ __forceinline__ float tanh_f(float x) {
  return 2.0f / (1.0f + __expf(-2.0f * x)) - 1.0f;
}

// ---------------------------------------------------------------------------
// Persistent LSTM recurrence.
// 64 blocks = 32 batch-groups (16 rows each) x 2 gate-halves.
// Each block holds its slice of [W_hh | W_ih] as bf16 MFMA B-fragments in
// VGPRs for all 1024 steps (160 VGPRs/lane). Per step:
//   gates[16,512] = [h(16x256) | x_t(16x64)] @ Wslice^T   (MFMA 16x16x32 bf16)
//   c,f,i,g,o update in fp32 regs; h -> bf16 -> hs (agent-scope atomics)
//   pair handshake via monotonic flag (release/acquire, agent scope)
// ---------------------------------------------------------------------------
__global__ __launch_bounds__(512, 2) void lstm_kernel(
    const float* __restrict__ x, const float* __restrict__ h0,
    const float* __restrict__ c0, const float* __restrict__ W_ih,
    const float* __restrict__ W_hh, const float* __restrict__ b_ih,
    const float* __restrict__ b_hh, unsigned* __restrict__ flags,
    uint16_t* __restrict__ hs) {
  const int tid   = threadIdx.x;
  const int blk   = blockIdx.x;
  const int group = blk >> 1;
  const int half  = blk & 1;
  const int b0    = group * 16;
  const int w     = tid >> 6;
  const int lane  = tid & 63;
  const int quad  = lane >> 4;
  const int l16   = lane & 15;
  const int partner = blk ^ 1;

  __shared__ short Alds[16 * 328];   // A = [h(256) | x(64)] bf16, padded stride
  __shared__ float Glds[16 * 516];   // gate preacts fp32, padded stride

  // ---- resident weight fragments: bw[kt][nt], kt 0..7 -> W_hh, 8..9 -> W_ih
  short8 bw[10][4];
#pragma unroll
  for (int kt = 0; kt < 10; ++kt) {
#pragma unroll
    for (int nt = 0; nt < 4; ++nt) {
      int n_loc = w * 64 + nt * 16 + l16;          // 0..511 within block
      int gate  = n_loc >> 7;                      // i,f,g,o
      int hh    = n_loc & 127;
      int grow  = gate * 256 + half * 128 + hh;    // row in 4H
      const float* src = (kt < 8)
          ? (W_hh + (size_t)grow * 256 + kt * 32 + quad * 8)
          : (W_ih + (size_t)grow * 64 + (kt - 8) * 32 + quad * 8);
      short8 bv;
#pragma unroll
      for (int j = 0; j < 8; ++j) bv[j] = f2bf(src[j]);
      bw[kt][nt] = bv;
    }
  }

  // ---- per-thread update-phase mapping: 4 cell elements
  const int urow = tid >> 5;            // batch row 0..15
  const int hh0  = (tid & 31) * 4;      // h-index within half, 0..124
  float bias[4][4];
  float c_reg[4];
#pragma unroll
  for (int g = 0; g < 4; ++g) {
    const float* bi = b_ih + g * 256 + half * 128 + hh0;
    const float* bh = b_hh + g * 256 + half * 128 + hh0;
#pragma unroll
    for (int r = 0; r < 4; ++r) bias[g][r] = bi[r] + bh[r];
  }
  {
    const float* c0p = c0 + (size_t)(b0 + urow) * 256 + half * 128 + hh0;
#pragma unroll
    for (int r = 0; r < 4; ++r) c_reg[r] = c0p[r];
  }

  // ---- init A-LDS: full h0 (both halves) + x(0)
  {
    int c8 = (tid & 31) * 8;
    const float* hp = h0 + (size_t)(b0 + urow) * 256 + c8;
    short8 hv;
#pragma unroll
    for (int j = 0; j < 8; ++j) hv[j] = f2bf(hp[j]);
    *(short8*)&Alds[urow * 328 + c8] = hv;

    int xc = (tid & 31) * 2;
    const float* xp = x + ((size_t)(b0 + urow) * T_STEPS + 0) * DIN + xc;
    short2v xv2; xv2[0] = f2bf(xp[0]); xv2[1] = f2bf(xp[1]);
    *(short2v*)&Alds[urow * 328 + 256 + xc] = xv2;
  }

  for (int t = 0; t < T_STEPS; ++t) {
    __syncthreads();  // A-LDS ready (h(t-1), x(t))

    // prefetch x(t+1) early (latency hidden behind MFMA phase)
    int tn = (t + 1 < T_STEPS) ? (t + 1) : t;
    int xc = (tid & 31) * 2;
    const float* xp = x + ((size_t)(b0 + urow) * T_STEPS + tn) * DIN + xc;
    float xa = xp[0], xb = xp[1];

    // gates = A @ Wslice^T
    float4v acc[4] = {{0.f,0.f,0.f,0.f},{0.f,0.f,0.f,0.f},
                      {0.f,0.f,0.f,0.f},{0.f,0.f,0.f,0.f}};
#pragma unroll
    for (int kt = 0; kt < 10; ++kt) {
      short8 a = *(const short8*)&Alds[l16 * 328 + kt * 32 + quad * 8];
#pragma unroll
      for (int nt = 0; nt < 4; ++nt)
        acc[nt] = __builtin_amdgcn_mfma_f32_16x16x32_bf16(a, bw[kt][nt], acc[nt], 0, 0, 0);
    }
    // preacts -> G-LDS  (D layout: col = l16, row = quad*4+r)
#pragma unroll
    for (int nt = 0; nt < 4; ++nt) {
      int col = w * 64 + nt * 16 + l16;
#pragma unroll
      for (int r = 0; r < 4; ++r)
        Glds[(quad * 4 + r) * 516 + col] = acc[nt][r];
    }
    __syncthreads();  // gates ready; A-LDS reads done -> safe to overwrite

    // ---- cell update (fp32 state in regs)
    float4v ip = *(const float4v*)&Glds[urow * 516 + 0   + hh0];
    float4v fp = *(const float4v*)&Glds[urow * 516 + 128 + hh0];
    float4v gp = *(const float4v*)&Glds[urow * 516 + 256 + hh0];
    float4v op = *(const float4v*)&Glds[urow * 516 + 384 + hh0];
    short hb[4];
#pragma unroll
    for (int r = 0; r < 4; ++r) {
      float iv = sigm(ip[r] + bias[0][r]);
      float fv = sigm(fp[r] + bias[1][r]);
      float gv = tanh_f(gp[r] + bias[2][r]);
      float ov = sigm(op[r] + bias[3][r]);
      float cv = fv * c_reg[r] + iv * gv;
      c_reg[r] = cv;
      hb[r] = f2bf(ov * tanh_f(cv));
    }
    // own half -> A-LDS
    short4v hv4; hv4[0] = hb[0]; hv4[1] = hb[1]; hv4[2] = hb[2]; hv4[3] = hb[3];
    *(short4v*)&Alds[urow * 328 + half * 128 + hh0] = hv4;
    // -> hs (partner + MLP). Agent-scope atomics: cache-bypassing, XCD-safe.
    unsigned long long hbits =
        (unsigned long long)(unsigned short)hb[0]
      | ((unsigned long long)(unsigned short)hb[1] << 16)
      | ((unsigned long long)(unsigned short)hb[2] << 32)
      | ((unsigned long long)(unsigned short)hb[3] << 48);
    size_t hidx = ((size_t)(b0 + urow) * T_STEPS + t) * HID + half * 128 + hh0;
    __hip_atomic_store((unsigned long long*)(hs + hidx), hbits,
                       __ATOMIC_RELAXED, __HIP_MEMORY_SCOPE_AGENT);
    // x(t+1) -> A-LDS
    short2v xv2; xv2[0] = f2bf(xa); xv2[1] = f2bf(xb);
    *(short2v*)&Alds[urow * 328 + 256 + xc] = xv2;

    if (t + 1 < T_STEPS) {
      __syncthreads();  // barrier drains vmcnt: hs stores complete before flag
      if (tid == 0) {
        __hip_atomic_store(&flags[blk], (unsigned)(t + 1),
                           __ATOMIC_RELEASE, __HIP_MEMORY_SCOPE_AGENT);
        int guard = 0;
        while (__hip_atomic_load(&flags[partner], __ATOMIC_ACQUIRE,
                                 __HIP_MEMORY_SCOPE_AGENT) < (unsigned)(t + 1)) {
          if (++guard > (1 << 26)) break;  // bounded: bug -> absmax, not hang
        }
      }
      __syncthreads();
      // partner half -> A-LDS
      size_t pidx = ((size_t)(b0 + urow) * T_STEPS + t) * HID + (1 - half) * 128 + hh0;
      unsigned long long pv = __hip_atomic_load((unsigned long long*)(hs + pidx),
                                                __ATOMIC_RELAXED, __HIP_MEMORY_SCOPE_AGENT);
      short4v pv4;
      pv4[0] = (short)(pv);       pv4[1] = (short)(pv >> 16);
      pv4[2] = (short)(pv >> 32); pv4[3] = (short)(pv >> 48);
      *(short4v*)&Alds[urow * 328 + (1 - half) * 128 + hh0] = pv4;
    }
  }
}

// ---------------------------------------------------------------------------
// Fused MLP head: y = relu(hs @ W1^T + b1) @ W2^T + b2, * mask.
// 8192 blocks x 64 rows. GEMM1 -> act in LDS (aliased over h tile) -> GEMM2
// computed as D = W2 * act^T so the 4 acc regs land on 4 consecutive out-chs
// (single float4 store per lane per tile).
// ---------------------------------------------------------------------------
__global__ __launch_bounds__(512, 2) void mlp_kernel(
    const uint16_t* __restrict__ hs, const float* __restrict__ W1,
    const float* __restrict__ b1, const float* __restrict__ W2,
    const float* __restrict__ b2, const float* __restrict__ mask,
    float* __restrict__ y) {
  const int tid   = threadIdx.x;
  const int rows0 = blockIdx.x * 64;
  const int w     = tid >> 6;
  const int lane  = tid & 63;
  const int quad  = lane >> 4;
  const int l16   = lane & 15;

  __shared__ short S[64 * 264];  // h tile, later aliased as act tile

  // stage h tile [64,256] bf16
#pragma unroll
  for (int kk = 0; kk < 4; ++kk) {
    int c   = tid + kk * 512;       // 0..2047 chunks of 8 bf16
    int row = c >> 5;
    int off = (c & 31) * 8;
    short8 v = *(const short8*)(hs + (size_t)(rows0 + row) * HID + off);
    *(short8*)&S[row * 264 + off] = v;
  }

  // W1 B-fragments (fp32 -> bf16 on the fly) ; wave w owns hidden cols [w*32, w*32+32)
  short8 bf1[2][8];
  float  b1v[2];
#pragma unroll
  for (int nt = 0; nt < 2; ++nt) {
    int n = w * 32 + nt * 16 + l16;
    b1v[nt] = b1[n];
#pragma unroll
    for (int kt = 0; kt < 8; ++kt) {
      const float* src = W1 + (size_t)n * 256 + kt * 32 + quad * 8;
      short8 bv;
#pragma unroll
      for (int j = 0; j < 8; ++j) bv[j] = f2bf(src[j]);
      bf1[nt][kt] = bv;
    }
  }
  __syncthreads();

  // GEMM1: act = relu(h @ W1^T + b1)
  float4v acc1[2][4];
#pragma unroll
  for (int nt = 0; nt < 2; ++nt)
#pragma unroll
    for (int mt = 0; mt < 4; ++mt) acc1[nt][mt] = (float4v){0.f,0.f,0.f,0.f};
#pragma unroll
  for (int kt = 0; kt < 8; ++kt) {
    short8 a[4];
#pragma unroll
    for (int mt = 0; mt < 4; ++mt)
      a[mt] = *(const short8*)&S[(mt * 16 + l16) * 264 + kt * 32 + quad * 8];
#pragma unroll
    for (int nt = 0; nt < 2; ++nt)
#pragma unroll
      for (int mt = 0; mt < 4; ++mt)
        acc1[nt][mt] = __builtin_amdgcn_mfma_f32_16x16x32_bf16(a[mt], bf1[nt][kt], acc1[nt][mt], 0, 0, 0);
  }
  __syncthreads();  // all h reads done before aliasing S as act

#pragma unroll
  for (int nt = 0; nt < 2; ++nt) {
    int col = w * 32 + nt * 16 + l16;
#pragma unroll
    for (int mt = 0; mt < 4; ++mt)
#pragma unroll
      for (int r = 0; r < 4; ++r) {
        float v = acc1[nt][mt][r] + b1v[nt];
        v = v > 0.f ? v : 0.f;
        S[(mt * 16 + quad * 4 + r) * 264 + col] = f2bf(v);
      }
  }
  __syncthreads();

  // GEMM2: D = W2 * act^T ; wave w: out-ch tile mt2 = w>>1, row tiles (w&1)*2+{0,1}
  const int mt2 = w >> 1;
  short8 a2[8];
#pragma unroll
  for (int kt = 0; kt < 8; ++kt) {
    const float* src = W2 + (size_t)(mt2 * 16 + l16) * 256 + kt * 32 + quad * 8;
    short8 av;
#pragma unroll
    for (int j = 0; j < 8; ++j) av[j] = f2bf(src[j]);
    a2[kt] = av;
  }
  float4v acc2[2] = {{0.f,0.f,0.f,0.f},{0.f,0.f,0.f,0.f}};
#pragma unroll
  for (int kt = 0; kt < 8; ++kt) {
#pragma unroll
    for (int nt2 = 0; nt2 < 2; ++nt2) {
      int n0 = ((w & 1) * 2 + nt2) * 16;
      short8 b = *(const short8*)&S[(n0 + l16) * 264 + kt * 32 + quad * 8];
      acc2[nt2] = __builtin_amdgcn_mfma_f32_16x16x32_bf16(a2[kt], b, acc2[nt2], 0, 0, 0);
    }
  }
  // epilogue: + b2, * mask, store float4 (4 consecutive out-channels)
  const float* b2p = b2 + mt2 * 16 + quad * 4;
  float b2v0 = b2p[0], b2v1 = b2p[1], b2v2 = b2p[2], b2v3 = b2p[3];
#pragma unroll
  for (int nt2 = 0; nt2 < 2; ++nt2) {
    int n = ((w & 1) * 2 + nt2) * 16 + l16;
    int R = rows0 + n;
    float m = mask[R];
    float4v out;
    out[0] = (acc2[nt2][0] + b2v0) * m;
    out[1] = (acc2[nt2][1] + b2v1) * m;
    out[2] = (acc2[nt2][2] + b2v2) * m;
    out[3] = (acc2[nt2][3] + b2v3) * m;
    *(float4v*)(y + (size_t)R * 64 + mt2 * 16 + quad * 4) = out;
  }
}

extern "C" void kernel_launch(void* const* d_in, const int* in_sizes, int n_in,
                              void* d_out, int out_size, void* d_ws, size_t ws_size,
                              hipStream_t stream) {
  (void)in_sizes; (void)n_in; (void)out_size; (void)ws_size;
  const float* x    = (const float*)d_in[0];
  const float* mask = (const float*)d_in[1];
  const float* h0   = (const float*)d_in[2];
  const float* c0   = (const float*)d_in[3];
  const float* W_ih = (const float*)d_in[4];
  const float* W_hh = (const float*)d_in[5];
  const float* b_ih = (const float*)d_in[6];
  const float* b_hh = (const float*)d_in[7];
  const float* W1   = (const float*)d_in[8];
  const float* b1   = (const float*)d_in[9];
  const float* W2   = (const float*)d_in[10];
  const float* b2   = (const float*)d_in[11];
  float* y = (float*)d_out;

  char* ws = (char*)d_ws;
  unsigned* flags = (unsigned*)ws;                 // 64 flags, poisoned -> must zero
  uint16_t* hs    = (uint16_t*)(ws + 4096);        // [B,T,H] bf16 = 256 MiB

  hipMemsetAsync(flags, 0, 4096, stream);
  lstm_kernel<<<64, 512, 0, stream>>>(x, h0, c0, W_ih, W_hh, b_ih, b_hh, flags, hs);
  mlp_kernel<<<8192, 512, 0, stream>>>(hs, W1, b1, W2, b2, mask, y);
}

// Round 2
// 3659.972 us; speedup vs baseline: 1.3060x; 1.3060x over previous
//
#include <hip/hip_runtime.h>
#include <stdint.h>
#include <stddef.h>

#define T_STEPS 1024
#define BATCH   512
#define HID     256
#define DIN     64

typedef __attribute__((ext_vector_type(8))) short short8;
typedef __attribute__((ext_vector_type(4))) short short4v;
typedef __attribute__((ext_vector_type(2))) short short2v;
typedef __attribute__((ext_vector_type(4))) float float4v;

static __device__ __forceinline__ short f2bf(float f) {
  union { float f; unsigned u; } v; v.f = f;
  unsigned r = (v.u + 0x7FFFu + ((v.u >> 16) & 1u)) >> 16;
  return (short)r;
}
static __device__ __forceinline__ float sigm(float x) {
  return 1.0f / (1.0f + __expf(-x));
}
static __device__ __forceinline__ float tanh_f(float x) {
  return 2.0f / (1.0f + __expf(-2.0f * x)) - 1.0f;
}

// ---------------------------------------------------------------------------
// Persistent LSTM recurrence. 64 blocks = 32 batch-groups x 2 gate-halves.
// Pair exchange of h goes through a small double-buffered MALL-resident
// region as fp32 words SELF-TAGGED in mantissa bit0 with step parity
// (tag = 1^((t>>1)&1); 0xAA poison has bit0=0 -> never false-accepts).
// No flag, no tid0 spin: each thread polls exactly the 4 words it needs.
// Own-half + x MFMA K-tiles are computed while partner data is in flight.
// Partner = blk ^ 32 (same-XCD under round-robin dispatch; perf-only).
// ---------------------------------------------------------------------------
__global__ __launch_bounds__(512, 2) void lstm_kernel(
    const float* __restrict__ x, const float* __restrict__ h0,
    const float* __restrict__ c0, const float* __restrict__ W_ih,
    const float* __restrict__ W_hh, const float* __restrict__ b_ih,
    const float* __restrict__ b_hh, float* __restrict__ exch,
    uint16_t* __restrict__ hs) {
  const int tid   = threadIdx.x;
  const int blk   = blockIdx.x;
  const int group = blk & 31;
  const int half  = blk >> 5;
  const int b0    = group * 16;
  const int w     = tid >> 6;
  const int lane  = tid & 63;
  const int quad  = lane >> 4;
  const int l16   = lane & 15;
  const int partner = blk ^ 32;

  __shared__ short Alds[16 * 328];   // A = [h(256) | x(64)] bf16
  __shared__ float Glds[16 * 516];   // gate preacts fp32

  // ---- resident weights, PERMUTED by half so register indices are static:
  // bw[0..3] = own-half h K-tiles, bw[4..7] = partner-half, bw[8..9] = x.
  short8 bw[10][4];
#pragma unroll
  for (int j = 0; j < 10; ++j) {
    int ktA = (j < 4) ? (half * 4 + j) : (j < 8) ? ((1 - half) * 4 + (j - 4)) : j;
#pragma unroll
    for (int nt = 0; nt < 4; ++nt) {
      int n_loc = w * 64 + nt * 16 + l16;          // 0..511 within block
      int gate  = n_loc >> 7;
      int hh    = n_loc & 127;
      int grow  = gate * 256 + half * 128 + hh;    // output row in 4H
      const float* src = (ktA < 8)
          ? (W_hh + (size_t)grow * 256 + ktA * 32 + quad * 8)
          : (W_ih + (size_t)grow * 64 + (ktA - 8) * 32 + quad * 8);
      short8 bv;
#pragma unroll
      for (int e = 0; e < 8; ++e) bv[e] = f2bf(src[e]);
      bw[j][nt] = bv;
    }
  }

  // ---- update-phase mapping: thread owns (urow, hh0..hh0+3) of its half
  const int urow = tid >> 5;
  const int hh0  = (tid & 31) * 4;
  const int xc   = (tid & 31) * 2;
  float bias[4][4];
  float c_reg[4];
#pragma unroll
  for (int g = 0; g < 4; ++g) {
    const float* bi = b_ih + g * 256 + half * 128 + hh0;
    const float* bh = b_hh + g * 256 + half * 128 + hh0;
#pragma unroll
    for (int r = 0; r < 4; ++r) bias[g][r] = bi[r] + bh[r];
  }
  {
    const float* c0p = c0 + (size_t)(b0 + urow) * 256 + half * 128 + hh0;
#pragma unroll
    for (int r = 0; r < 4; ++r) c_reg[r] = c0p[r];
  }

  // exchange word pointers (2 x u64 per thread per buffer)
  const int widx = urow * 64 + (hh0 >> 1);
  unsigned long long* sbuf[2];
  const unsigned long long* pbuf[2];
#pragma unroll
  for (int bfi = 0; bfi < 2; ++bfi) {
    sbuf[bfi] = (unsigned long long*)(exch + ((size_t)blk * 2 + bfi) * 2048) + widx;
    pbuf[bfi] = (const unsigned long long*)(exch + ((size_t)partner * 2 + bfi) * 2048) + widx;
  }

  // ---- init A-LDS: full h0 + x(0)
  {
    int c8 = (tid & 31) * 8;
    const float* hp = h0 + (size_t)(b0 + urow) * 256 + c8;
    short8 hv;
#pragma unroll
    for (int e = 0; e < 8; ++e) hv[e] = f2bf(hp[e]);
    *(short8*)&Alds[urow * 328 + c8] = hv;
    const float* xp = x + ((size_t)(b0 + urow) * T_STEPS + 0) * DIN + xc;
    short2v xv2; xv2[0] = f2bf(xp[0]); xv2[1] = f2bf(xp[1]);
    *(short2v*)&Alds[urow * 328 + 256 + xc] = xv2;
  }
  __syncthreads();

  const int ownbase = half * 128;
  const int pbase   = (1 - half) * 128;

  for (int t = 0; t < T_STEPS; ++t) {
    // ---- phase 1: own-half h tiles + x tiles (no exchange needed)
    float4v acc[4] = {{0.f,0.f,0.f,0.f},{0.f,0.f,0.f,0.f},
                      {0.f,0.f,0.f,0.f},{0.f,0.f,0.f,0.f}};
    int tn = (t + 1 < T_STEPS) ? (t + 1) : t;
    const float* xp = x + ((size_t)(b0 + urow) * T_STEPS + tn) * DIN + xc;
    float xa = xp[0], xb = xp[1];

#pragma unroll
    for (int j = 0; j < 4; ++j) {
      short8 a = *(const short8*)&Alds[l16 * 328 + ownbase + j * 32 + quad * 8];
#pragma unroll
      for (int nt = 0; nt < 4; ++nt)
        acc[nt] = __builtin_amdgcn_mfma_f32_16x16x32_bf16(a, bw[j][nt], acc[nt], 0, 0, 0);
    }
#pragma unroll
    for (int j = 8; j < 10; ++j) {
      short8 a = *(const short8*)&Alds[l16 * 328 + 256 + (j - 8) * 32 + quad * 8];
#pragma unroll
      for (int nt = 0; nt < 4; ++nt)
        acc[nt] = __builtin_amdgcn_mfma_f32_16x16x32_bf16(a, bw[j][nt], acc[nt], 0, 0, 0);
    }

    // ---- poll partner's self-tagged h(t-1) words (overlapped with phase 1)
    if (t > 0) {
      int buf = (t - 1) & 1;
      unsigned tag = 1u ^ (((unsigned)(t - 1) >> 1) & 1u);
      const unsigned long long* p = pbuf[buf];
      unsigned long long w0, w1;
      int guard = 0;
      for (;;) {
        w0 = __hip_atomic_load(p,     __ATOMIC_RELAXED, __HIP_MEMORY_SCOPE_AGENT);
        w1 = __hip_atomic_load(p + 1, __ATOMIC_RELAXED, __HIP_MEMORY_SCOPE_AGENT);
        bool ok = (((unsigned)w0 & 1u) == tag) & ((((unsigned)(w0 >> 32)) & 1u) == tag) &
                  (((unsigned)w1 & 1u) == tag) & ((((unsigned)(w1 >> 32)) & 1u) == tag);
        if (ok) break;
        if (++guard > 4096) break;   // bounded: bug -> absmax fail, not hang
      }
      union { unsigned u; float f; } f0, f1, f2, f3;
      f0.u = (unsigned)w0; f1.u = (unsigned)(w0 >> 32);
      f2.u = (unsigned)w1; f3.u = (unsigned)(w1 >> 32);
      short4v pv4;
      pv4[0] = f2bf(f0.f); pv4[1] = f2bf(f1.f);
      pv4[2] = f2bf(f2.f); pv4[3] = f2bf(f3.f);
      *(short4v*)&Alds[urow * 328 + pbase + hh0] = pv4;
    }
    __syncthreads();   // partner region ready

    // ---- phase 2: partner-half h tiles
#pragma unroll
    for (int j = 4; j < 8; ++j) {
      short8 a = *(const short8*)&Alds[l16 * 328 + pbase + (j - 4) * 32 + quad * 8];
#pragma unroll
      for (int nt = 0; nt < 4; ++nt)
        acc[nt] = __builtin_amdgcn_mfma_f32_16x16x32_bf16(a, bw[j][nt], acc[nt], 0, 0, 0);
    }
    // preacts -> G-LDS (D layout: col=l16, row=quad*4+r)
#pragma unroll
    for (int nt = 0; nt < 4; ++nt) {
      int col = w * 64 + nt * 16 + l16;
#pragma unroll
      for (int r = 0; r < 4; ++r)
        Glds[(quad * 4 + r) * 516 + col] = acc[nt][r];
    }
    __syncthreads();   // gates ready; A-LDS reads done

    // ---- cell update (fp32 state in regs)
    float4v ip = *(const float4v*)&Glds[urow * 516 + 0   + hh0];
    float4v fp = *(const float4v*)&Glds[urow * 516 + 128 + hh0];
    float4v gp = *(const float4v*)&Glds[urow * 516 + 256 + hh0];
    float4v op = *(const float4v*)&Glds[urow * 516 + 384 + hh0];
    float hf[4];
    short hb[4];
#pragma unroll
    for (int r = 0; r < 4; ++r) {
      float iv = sigm(ip[r] + bias[0][r]);
      float fv = sigm(fp[r] + bias[1][r]);
      float gv = tanh_f(gp[r] + bias[2][r]);
      float ov = sigm(op[r] + bias[3][r]);
      float cv = fv * c_reg[r] + iv * gv;
      c_reg[r] = cv;
      hf[r] = ov * tanh_f(cv);
      hb[r] = f2bf(hf[r]);
    }
    // self-tagged exchange store FIRST (earliest visibility to partner)
    {
      int buf = t & 1;
      unsigned tag = 1u ^ (((unsigned)t >> 1) & 1u);
      union { float f; unsigned u; } u0, u1, u2, u3;
      u0.f = hf[0]; u1.f = hf[1]; u2.f = hf[2]; u3.f = hf[3];
      unsigned long long w0 = (unsigned long long)((u0.u & ~1u) | tag)
                            | ((unsigned long long)((u1.u & ~1u) | tag) << 32);
      unsigned long long w1 = (unsigned long long)((u2.u & ~1u) | tag)
                            | ((unsigned long long)((u3.u & ~1u) | tag) << 32);
      __hip_atomic_store(sbuf[buf],     w0, __ATOMIC_RELAXED, __HIP_MEMORY_SCOPE_AGENT);
      __hip_atomic_store(sbuf[buf] + 1, w1, __ATOMIC_RELAXED, __HIP_MEMORY_SCOPE_AGENT);
    }
    // own half -> A-LDS
    short4v hv4; hv4[0] = hb[0]; hv4[1] = hb[1]; hv4[2] = hb[2]; hv4[3] = hb[3];
    *(short4v*)&Alds[urow * 328 + ownbase + hh0] = hv4;
    // hs for MLP: plain cached store (kernel boundary provides visibility)
    *(short4v*)(hs + ((size_t)(b0 + urow) * T_STEPS + t) * HID + ownbase + hh0) = hv4;
    // x(t+1) -> A-LDS
    short2v xv2; xv2[0] = f2bf(xa); xv2[1] = f2bf(xb);
    *(short2v*)&Alds[urow * 328 + 256 + xc] = xv2;
    __syncthreads();   // own half + x ready for next phase 1
  }
}

// ---------------------------------------------------------------------------
// One-time fp32 -> bf16 conversion of MLP weights into workspace.
// ---------------------------------------------------------------------------
__global__ void prep_kernel(const float* __restrict__ W1, const float* __restrict__ W2,
                            short* __restrict__ W1b, short* __restrict__ W2b) {
  int i = blockIdx.x * 512 + threadIdx.x;   // 160*512 = 81920 = 65536 + 16384
  if (i < 65536) W1b[i] = f2bf(W1[i]);
  else           W2b[i - 65536] = f2bf(W2[i - 65536]);
}

// ---------------------------------------------------------------------------
// Fused MLP head: y = relu(hs @ W1^T + b1) @ W2^T + b2, * mask.
// 4096 blocks x 128 rows (weights amortized over 2x more rows than R1,
// and loaded as bf16 -> 4x less weight traffic per row).
// ---------------------------------------------------------------------------
__global__ __launch_bounds__(512, 2) void mlp_kernel(
    const uint16_t* __restrict__ hs, const short* __restrict__ W1b,
    const float* __restrict__ b1, const short* __restrict__ W2b,
    const float* __restrict__ b2, const float* __restrict__ mask,
    float* __restrict__ y) {
  const int tid   = threadIdx.x;
  const int rows0 = blockIdx.x * 128;
  const int w     = tid >> 6;
  const int lane  = tid & 63;
  const int quad  = lane >> 4;
  const int l16   = lane & 15;

  __shared__ short S[128 * 264];  // h tile, later aliased as act tile

  // stage h tile [128,256] bf16
#pragma unroll
  for (int kk = 0; kk < 8; ++kk) {
    int c   = tid + kk * 512;
    int row = c >> 5;
    int off = (c & 31) * 8;
    *(short8*)&S[row * 264 + off] =
        *(const short8*)(hs + (size_t)(rows0 + row) * HID + off);
  }

  // W1 B-fragments; wave w owns hidden cols [w*32, w*32+32)
  short8 bf1[2][8];
  float  b1v[2];
#pragma unroll
  for (int nt = 0; nt < 2; ++nt) {
    int n = w * 32 + nt * 16 + l16;
    b1v[nt] = b1[n];
#pragma unroll
    for (int kt = 0; kt < 8; ++kt)
      bf1[nt][kt] = *(const short8*)(W1b + (size_t)n * 256 + kt * 32 + quad * 8);
  }
  __syncthreads();

  // GEMM1: act = relu(h @ W1^T + b1), 8 M-tiles
  float4v acc1[2][8];
#pragma unroll
  for (int nt = 0; nt < 2; ++nt)
#pragma unroll
    for (int mt = 0; mt < 8; ++mt) acc1[nt][mt] = (float4v){0.f,0.f,0.f,0.f};
#pragma unroll
  for (int kt = 0; kt < 8; ++kt) {
#pragma unroll
    for (int mt = 0; mt < 8; ++mt) {
      short8 a = *(const short8*)&S[(mt * 16 + l16) * 264 + kt * 32 + quad * 8];
#pragma unroll
      for (int nt = 0; nt < 2; ++nt)
        acc1[nt][mt] = __builtin_amdgcn_mfma_f32_16x16x32_bf16(a, bf1[nt][kt], acc1[nt][mt], 0, 0, 0);
    }
  }
  __syncthreads();  // all h reads done before aliasing S as act

#pragma unroll
  for (int nt = 0; nt < 2; ++nt) {
    int col = w * 32 + nt * 16 + l16;
#pragma unroll
    for (int mt = 0; mt < 8; ++mt)
#pragma unroll
      for (int r = 0; r < 4; ++r) {
        float v = acc1[nt][mt][r] + b1v[nt];
        v = v > 0.f ? v : 0.f;
        S[(mt * 16 + quad * 4 + r) * 264 + col] = f2bf(v);
      }
  }
  __syncthreads();

  // GEMM2: D = W2 * act^T ; wave w: out-ch tile mt2=w>>1, row half (w&1)
  const int mt2 = w >> 1;
  short8 a2[8];
#pragma unroll
  for (int kt = 0; kt < 8; ++kt)
    a2[kt] = *(const short8*)(W2b + (size_t)(mt2 * 16 + l16) * 256 + kt * 32 + quad * 8);
  float4v acc2[4] = {{0.f,0.f,0.f,0.f},{0.f,0.f,0.f,0.f},
                     {0.f,0.f,0.f,0.f},{0.f,0.f,0.f,0.f}};
#pragma unroll
  for (int kt = 0; kt < 8; ++kt) {
#pragma unroll
    for (int nt2 = 0; nt2 < 4; ++nt2) {
      int n0 = (w & 1) * 64 + nt2 * 16;
      short8 b = *(const short8*)&S[(n0 + l16) * 264 + kt * 32 + quad * 8];
      acc2[nt2] = __builtin_amdgcn_mfma_f32_16x16x32_bf16(a2[kt], b, acc2[nt2], 0, 0, 0);
    }
  }
  const float* b2p = b2 + mt2 * 16 + quad * 4;
  float b2v0 = b2p[0], b2v1 = b2p[1], b2v2 = b2p[2], b2v3 = b2p[3];
#pragma unroll
  for (int nt2 = 0; nt2 < 4; ++nt2) {
    int R = rows0 + (w & 1) * 64 + nt2 * 16 + l16;
    float m = mask[R];
    float4v out;
    out[0] = (acc2[nt2][0] + b2v0) * m;
    out[1] = (acc2[nt2][1] + b2v1) * m;
    out[2] = (acc2[nt2][2] + b2v2) * m;
    out[3] = (acc2[nt2][3] + b2v3) * m;
    *(float4v*)(y + (size_t)R * 64 + mt2 * 16 + quad * 4) = out;
  }
}

extern "C" void kernel_launch(void* const* d_in, const int* in_sizes, int n_in,
                              void* d_out, int out_size, void* d_ws, size_t ws_size,
                              hipStream_t stream) {
  (void)in_sizes; (void)n_in; (void)out_size; (void)ws_size;
  const float* x    = (const float*)d_in[0];
  const float* mask = (const float*)d_in[1];
  const float* h0   = (const float*)d_in[2];
  const float* c0   = (const float*)d_in[3];
  const float* W_ih = (const float*)d_in[4];
  const float* W_hh = (const float*)d_in[5];
  const float* b_ih = (const float*)d_in[6];
  const float* b_hh = (const float*)d_in[7];
  const float* W1   = (const float*)d_in[8];
  const float* b1   = (const float*)d_in[9];
  const float* W2   = (const float*)d_in[10];
  const float* b2   = (const float*)d_in[11];
  float* y = (float*)d_out;

  char* ws = (char*)d_ws;
  float*    exch = (float*)ws;                        // 1 MiB, self-tagged (no memset needed)
  short*    W1b  = (short*)(ws + (1u << 20));         // 128 KiB
  short*    W2b  = (short*)(ws + (1u << 20) + 131072);// 32 KiB
  uint16_t* hs   = (uint16_t*)(ws + (2u << 20));      // [B,T,H] bf16 = 256 MiB

  prep_kernel<<<160, 512, 0, stream>>>(W1, W2, W1b, W2b);
  lstm_kernel<<<64, 512, 0, stream>>>(x, h0, c0, W_ih, W_hh, b_ih, b_hh, exch, hs);
  mlp_kernel<<<4096, 512, 0, stream>>>(hs, W1b, b1, W2b, b2, mask, y);
}